// Round 1
// 381.540 us; speedup vs baseline: 1.0023x; 1.0023x over previous
//
#include <hip/hip_runtime.h>
#include <hip/hip_bf16.h>
#include <hip/hip_fp16.h>

// Problem constants (GuidedSampler): B=32, DIM=512, H=64, W=64, K=64, DQ=3
#define BN   32
#define DIMK 512
#define HW   4096
#define KK   64
#define DQ   3
#define RR   192            // KK*DQ GEMM rows
#define NT   128            // hw columns per block
#define NBLK (HW / NT)      // 32
#define NKK  (DIMK / 32)    // 16 k-slices

#define AP_ROW   40             // padded halfs per A row slice (80 B rows)
#define AP_SLICE (RR * AP_ROW)  // 7680 halfs = 15360 B per kk slice

typedef _Float16 half8  __attribute__((ext_vector_type(8)));
typedef _Float16 half4  __attribute__((ext_vector_type(4)));
typedef float    f32x4  __attribute__((ext_vector_type(4)));
typedef short    short8 __attribute__((ext_vector_type(8)));

// Workspace layout
#define AP_OFF     0
#define AP_BYTES   (NKK * AP_SLICE * 2)            // 245760: W fp16, padded [kk][192][40]
#define DIST2_OFF  245760
#define DIST2_BYTES (BN * KK * 4)                  // 8192
#define KV_OFF     262144
#define KV_BYTES   ((size_t)BN * RR * HW * 2)      // 50331648 (kv as bf16)

#define OUT_SEL    ((size_t)BN * DQ * HW)          // codes offset in out
#define OUT_LOSS   (OUT_SEL + BN)

// ---------------------------------------------------------------------------
// Kernel 1: W fp32 -> fp16 into the PADDED per-kk-slice image [kk][192][40]
// (exactly the LDS layout; gemm stages it with linear global_load_lds).
// Also zero dist2 and the loss slot. (ws/out re-poisoned 0xAA each call.)
__global__ void init_kernel(const float* __restrict__ Wsrc,
                            _Float16* __restrict__ Ap,
                            float* __restrict__ dist2,
                            float* __restrict__ out) {
  int gid = blockIdx.x * 256 + threadIdx.x;   // grid = 96 blocks
  int d4 = gid * 4;
  if (d4 < RR * DIMK) {
    f32x4 v = *(const f32x4*)&Wsrc[d4];
    half4 h;
#pragma unroll
    for (int j = 0; j < 4; j++) h[j] = (_Float16)v[j];
    int m = d4 >> 9;          // row 0..191
    int d = d4 & 511;         // k 0..511 (4-aligned, stays within a 32-chunk)
    *(half4*)&Ap[((size_t)(d >> 5) * RR + m) * AP_ROW + (d & 31)] = h;
  }
  if (gid < BN * KK) dist2[gid] = 0.f;
  if (gid == 0)      out[OUT_LOSS] = 0.f;
}

// ---------------------------------------------------------------------------
// Kernel 2: per (b, hw-tile): C[192][128] = W_f16(192x512) * f(512x128).
// A: global_load_lds dwordx4 straight into double-buffered padded LDS (no
//    VGPR roundtrip; 15 coalesced 1KiB wave-copies per slice).
// B: register-prefetched fp32, converted fp16 at stage time, double-buffered.
// ONE barrier per K-iter. __launch_bounds__(256,3): 3 blocks/CU (12 waves),
// LDS = 49.4 KB * 3 = 148 KB <= 160.
// MFMA 16x16x32 f16 layouts (m89/m91 family):
//   A[m=lane&15][k=quad*8+j], B[k=quad*8+j][n=lane&15], C: col=lane&15,row=quad*4+reg
template <bool STORE>
__global__ __launch_bounds__(256, 3) void gemm_dist_kernel(
    const float* __restrict__ f, const float* __restrict__ query,
    const _Float16* __restrict__ Ap, __hip_bfloat16* __restrict__ kv,
    float* __restrict__ dist2) {
  __shared__ __align__(16) _Float16 Alds[2][RR][AP_ROW];  // 30720 B
  __shared__ __align__(16) _Float16 Blds[2][4][NT][8];    // 16384 B
  __shared__ float qlds[DQ][NT];                          // 1536 B
  __shared__ float rowsum[RR];                            // 768 B

  const int t  = threadIdx.x;
  const int w  = t >> 6;        // wave id: rows [48w, 48w+48)
  const int l  = t & 63;
  const int lq = l >> 4;        // quad
  const int ln = l & 15;
  const int b  = blockIdx.y;
  const int n0 = blockIdx.x * NT;

  for (int s = t; s < DQ * NT; s += 256) {
    int q = s / NT, n = s % NT;
    qlds[q][n] = query[((size_t)b * DQ + q) * HW + n0 + n];
  }

  f32x4 acc[3][8];
#pragma unroll
  for (int mt = 0; mt < 3; mt++)
#pragma unroll
    for (int nt = 0; nt < 8; nt++) acc[mt][nt] = (f32x4)0.f;

  // B staging decomposition: thread = (column bn, k-half bkb)
  const int bn  = t & (NT - 1);   // 0..127
  const int bkb = t >> 7;         // 0..1 -> k rows [16*bkb, 16*bkb+16)
  const float* fbase = f + ((size_t)b * DIMK + bkb * 16) * HW + n0 + bn;

  float bpre[16];     // B prefetch regs (fp32, converted at stage time)

  auto loadTile = [&](int kk) {
    const float* fp = fbase + (size_t)kk * 32 * HW;
#pragma unroll
    for (int j = 0; j < 16; j++) bpre[j] = fp[(size_t)j * HW];
  };
  auto stageTile = [&](int buf) {
    half8 h0, h1;
#pragma unroll
    for (int j = 0; j < 8; j++) { h0[j] = (_Float16)bpre[j]; h1[j] = (_Float16)bpre[8 + j]; }
    *(half8*)&Blds[buf][2 * bkb][bn][0]     = h0;
    *(half8*)&Blds[buf][2 * bkb + 1][bn][0] = h1;
  };
  // A slice kk -> Alds[buf] : linear 15360 B copy, 15 x (64 lanes x 16 B).
  // Wave w issues slots {w, w+4, w+8, w+12} (w=3 gets 3). Branch is
  // wave-uniform. LDS dest is wave-uniform base + lane*16 (HW rule).
  auto stageA = [&](int kk, int buf) {
    const char* gs = (const char*)Ap + (size_t)kk * (AP_SLICE * 2) + (size_t)l * 16;
    char* ls = (char*)&Alds[buf][0][0];
#pragma unroll
    for (int jj = 0; jj < 4; jj++) {
      int i = w + 4 * jj;
      if (jj < 3 || w < 3) {
        __builtin_amdgcn_global_load_lds(
            (const __attribute__((address_space(1))) unsigned int*)(const void*)(gs + i * 1024),
            (__attribute__((address_space(3))) unsigned int*)(void*)(ls + i * 1024),
            16, 0, 0);
      }
    }
  };

  loadTile(0);        // B loads first: stageTile's ds_write only needs these
  stageA(0, 0);       // A load_lds drains at the barrier
  stageTile(0);
  for (int kk = 0; kk < NKK; kk++) {
    const int cur = kk & 1;
    __syncthreads();                       // buf[cur] ready; buf[cur^1] free
    if (kk < NKK - 1) {
      loadTile(kk + 1);                    // B regs in flight across the MFMAs
      stageA(kk + 1, cur ^ 1);             // A -> LDS in flight across the MFMAs
    }

    half8 af[3];
#pragma unroll
    for (int mt = 0; mt < 3; mt++)
      af[mt] = *(const half8*)&Alds[cur][w * 48 + mt * 16 + ln][lq * 8];
#pragma unroll
    for (int g = 0; g < 2; g++) {          // grouped: bf liveness = 4 regs
      half8 bf[4];
#pragma unroll
      for (int nt = 0; nt < 4; nt++)
        bf[nt] = *(const half8*)&Blds[cur][lq][(g * 4 + nt) * 16 + ln][0];
#pragma unroll
      for (int mt = 0; mt < 3; mt++)
#pragma unroll
        for (int nt = 0; nt < 4; nt++)
          acc[mt][g * 4 + nt] = __builtin_amdgcn_mfma_f32_16x16x32_f16(
              af[mt], bf[nt], acc[mt][g * 4 + nt], 0, 0, 0);
    }
    if (kk < NKK - 1) stageTile(cur ^ 1);
  }

  // Epilogue: kv store + per-row sq-diff partials
  float rs[3][4];
#pragma unroll
  for (int mt = 0; mt < 3; mt++)
#pragma unroll
    for (int i = 0; i < 4; i++) rs[mt][i] = 0.f;

#pragma unroll
  for (int mt = 0; mt < 3; mt++) {
#pragma unroll
    for (int i = 0; i < 4; i++) {
      int r = w * 48 + mt * 16 + lq * 4 + i;   // global row 0..191
      int q = r % 3;
#pragma unroll
      for (int nt = 0; nt < 8; nt++) {
        int n = nt * 16 + ln;
        float c = acc[mt][nt][i];
        if (STORE) kv[((size_t)b * RR + r) * HW + n0 + n] = __float2bfloat16(c);
        float d = c - qlds[q][n];
        rs[mt][i] += d * d;
      }
    }
  }
  // butterfly over low 4 lane bits (sums the 16 columns within a quad)
#pragma unroll
  for (int mt = 0; mt < 3; mt++)
#pragma unroll
    for (int i = 0; i < 4; i++) {
      float v = rs[mt][i];
      v += __shfl_xor(v, 1, 64);
      v += __shfl_xor(v, 2, 64);
      v += __shfl_xor(v, 4, 64);
      v += __shfl_xor(v, 8, 64);
      rs[mt][i] = v;
    }
  if (ln < 12) {
    int mt = ln >> 2, i = ln & 3;
    rowsum[w * 48 + mt * 16 + lq * 4 + i] = rs[mt][i];
  }
  __syncthreads();
  if (t < KK) {
    float v = rowsum[3 * t] + rowsum[3 * t + 1] + rowsum[3 * t + 2];
    atomicAdd(&dist2[b * KK + t], v);  // device-scope, cross-XCD safe
  }
}

// ---------------------------------------------------------------------------
// Kernel 3a (STORE path): lane-parallel argmin, write codes, gather kv[b][code],
// loss atomic. Grid (4, BN): 4 chunks per batch for latency.
__global__ __launch_bounds__(256) void gather_kernel(
    const __hip_bfloat16* __restrict__ kv, const float* __restrict__ query,
    const float* __restrict__ dist2, float* __restrict__ out) {
  int b = blockIdx.y, t = threadIdx.x;
  __shared__ int scode;
  __shared__ float red[4];
  if (t < 64) {
    float v = dist2[b * KK + t];
    int idx = t;
#pragma unroll
    for (int off = 1; off < 64; off <<= 1) {
      float ov = __shfl_xor(v, off, 64);
      int   oi = __shfl_xor(idx, off, 64);
      if (ov < v || (ov == v && oi < idx)) { v = ov; idx = oi; }  // first-min tie-break
    }
    if (t == 0) {
      scode = idx;
      if (blockIdx.x == 0) out[OUT_SEL + b] = (float)idx;   // codes chunk, as float
    }
  }
  __syncthreads();
  int code = scode;
  const short8* src = (const short8*)(kv + ((size_t)b * RR + code * DQ) * HW);
  const f32x4*  qp  = (const f32x4*)(query + (size_t)b * DQ * HW);
  f32x4*        op  = (f32x4*)(out + (size_t)b * DQ * HW);
  float lsum = 0.f;
  const int c0 = blockIdx.x * 384;          // 1536 short8 chunks / 4 blocks
  for (int c = c0 + t; c < c0 + 384; c += 256) {
    short8 v = src[c];
    f32x4 o0, o1;
#pragma unroll
    for (int j = 0; j < 4; j++) {
      unsigned u0 = ((unsigned)(unsigned short)v[j]) << 16;
      unsigned u1 = ((unsigned)(unsigned short)v[4 + j]) << 16;
      o0[j] = __builtin_bit_cast(float, u0);
      o1[j] = __builtin_bit_cast(float, u1);
    }
    f32x4 q0 = qp[2 * c], q1 = qp[2 * c + 1];
    op[2 * c] = o0; op[2 * c + 1] = o1;
#pragma unroll
    for (int j = 0; j < 4; j++) {
      float d0 = o0[j] - q0[j], d1 = o1[j] - q1[j];
      lsum += d0 * d0 + d1 * d1;
    }
  }
  for (int off = 1; off < 64; off <<= 1) lsum += __shfl_xor(lsum, off, 64);
  if ((t & 63) == 0) red[t >> 6] = lsum;
  __syncthreads();
  if (t == 0)
    atomicAdd(&out[OUT_LOSS],
              (red[0] + red[1] + red[2] + red[3]) * (1.f / (float)(BN * DQ * HW)));
}

// ---------------------------------------------------------------------------
// Kernel 3b (fallback if ws too small): recompute selected kv from features
__global__ __launch_bounds__(256) void recompute_kernel(
    const float* __restrict__ f, const float* __restrict__ query,
    const float* __restrict__ Wsrc, const float* __restrict__ dist2,
    float* __restrict__ out) {
  int b = blockIdx.y, t = threadIdx.x;
  int hw = blockIdx.x * 256 + t;
  __shared__ int scode;
  __shared__ float red[4];
  if (t == 0) {
    float best = dist2[b * KK]; int bi = 0;
    for (int k = 1; k < KK; k++) {
      float v = dist2[b * KK + k];
      if (v < best) { best = v; bi = k; }
    }
    scode = bi;
    if (blockIdx.x == 0) out[OUT_SEL + b] = (float)bi;
  }
  __syncthreads();
  int code = scode;
  const float* w0 = Wsrc + (size_t)code * DQ * DIMK;
  const float* fp = f + (size_t)b * DIMK * HW + hw;
  float a0 = 0.f, a1 = 0.f, a2 = 0.f;
  for (int d = 0; d < DIMK; d++) {
    float fv = fp[(size_t)d * HW];
    a0 += w0[d] * fv;
    a1 += w0[DIMK + d] * fv;
    a2 += w0[2 * DIMK + d] * fv;
  }
  const float* qp = query + (size_t)b * DQ * HW;
  float* op = out + (size_t)b * DQ * HW;
  op[hw] = a0; op[HW + hw] = a1; op[2 * HW + hw] = a2;
  float d0 = a0 - qp[hw], d1 = a1 - qp[HW + hw], d2 = a2 - qp[2 * HW + hw];
  float lsum = d0 * d0 + d1 * d1 + d2 * d2;
  for (int off = 1; off < 64; off <<= 1) lsum += __shfl_xor(lsum, off, 64);
  if ((t & 63) == 0) red[t >> 6] = lsum;
  __syncthreads();
  if (t == 0)
    atomicAdd(&out[OUT_LOSS],
              (red[0] + red[1] + red[2] + red[3]) * (1.f / (float)(BN * DQ * HW)));
}

extern "C" void kernel_launch(void* const* d_in, const int* in_sizes, int n_in,
                              void* d_out, int out_size, void* d_ws, size_t ws_size,
                              hipStream_t stream) {
  const float* f     = (const float*)d_in[0];
  const float* query = (const float*)d_in[1];
  const float* Wsrc  = (const float*)d_in[2];
  float* out = (float*)d_out;
  char*  ws  = (char*)d_ws;

  _Float16*        Ap    = (_Float16*)(ws + AP_OFF);
  float*           dist2 = (float*)(ws + DIST2_OFF);
  __hip_bfloat16*  kv    = (__hip_bfloat16*)(ws + KV_OFF);

  // Deterministic host-side branch (same every call -> graph-capture safe)
  const bool store = ws_size >= (size_t)KV_OFF + KV_BYTES;

  init_kernel<<<96, 256, 0, stream>>>(Wsrc, Ap, dist2, out);
  if (store) {
    gemm_dist_kernel<true><<<dim3(NBLK, BN), 256, 0, stream>>>(f, query, Ap, kv, dist2);
    gather_kernel<<<dim3(4, BN), 256, 0, stream>>>(kv, query, dist2, out);
  } else {
    gemm_dist_kernel<false><<<dim3(NBLK, BN), 256, 0, stream>>>(f, query, Ap, nullptr, dist2);
    recompute_kernel<<<dim3(HW / 256, BN), 256, 0, stream>>>(f, query, Wsrc, dist2, out);
  }
}